// Round 2
// 823.572 us; speedup vs baseline: 1.0800x; 1.0800x over previous
//
#include <hip/hip_runtime.h>
#include <hip/hip_bf16.h>

typedef __hip_bfloat16 bf16;
typedef __bf16  bf16x8 __attribute__((ext_vector_type(8)));
typedef float   f32x4  __attribute__((ext_vector_type(4)));

static constexpr int DMODEL = 1024;
static constexpr int NHEADS = 16;
static constexpr int DHEAD  = 64;
static constexpr int BATCH  = 2;
static constexpr int SLQ    = 1024;
static constexpr int SLK    = 2048;
static constexpr size_t OUTQ = (size_t)BATCH * SLQ * DMODEL;   // out elems (f32)

// ---------------------------------------------------------------------------
// Stage 8 contiguous elements into LDS as bf16 (converting if source is f32).
// ---------------------------------------------------------------------------
__device__ __forceinline__ void stage8(unsigned short* dst, const bf16* src) {
    *(int4*)dst = *(const int4*)src;
}
__device__ __forceinline__ void stage8(unsigned short* dst, const float* src) {
    const float4 a = *(const float4*)(src);
    const float4 b = *(const float4*)(src + 4);
    bf16 h[8];
    h[0] = __float2bfloat16(a.x); h[1] = __float2bfloat16(a.y);
    h[2] = __float2bfloat16(a.z); h[3] = __float2bfloat16(a.w);
    h[4] = __float2bfloat16(b.x); h[5] = __float2bfloat16(b.y);
    h[6] = __float2bfloat16(b.z); h[7] = __float2bfloat16(b.w);
    *(int4*)dst = *(const int4*)h;
}

__device__ __forceinline__ void store_one(bf16* p, float v) { *p = __float2bfloat16(v); }
__device__ __forceinline__ void store_one(float* p, float v) { *p = v; }

// ---------------------------------------------------------------------------
// Core 64x64 tile GEMM:  C_tile = A_tile (64 x K) * B_tile^T (K x 64)
// 256 threads = 4 waves in 2x2; each wave a 32x32 sub-tile via 2x2
// v_mfma_f32_16x16x32_bf16.
// A/B frag: elem[m = lane&15][k = (lane>>4)*8 + j]
// C/D frag: col = lane&15, row = (lane>>4)*4 + reg
// ---------------------------------------------------------------------------
template <typename TA, typename TB>
__device__ __forceinline__ void gemm_core(const TA* __restrict__ At, int lda,
                                          const TB* __restrict__ Bt, int ldb,
                                          int K, f32x4 acc[2][2])
{
    __shared__ __align__(16) unsigned short As[64][40];
    __shared__ __align__(16) unsigned short Bs[64][40];
    const int tid  = threadIdx.x;
    const int lane = tid & 63;
    const int wave = tid >> 6;
    const int wr   = (wave >> 1) * 32;
    const int wc   = (wave & 1) * 32;
    const int lrow = lane & 15;
    const int koff = (lane >> 4) * 8;
    const int srow   = tid >> 2;
    const int schunk = (tid & 3) * 8;

    for (int kt = 0; kt < K; kt += 32) {
        stage8(&As[srow][schunk], At + (size_t)srow * lda + kt + schunk);
        stage8(&Bs[srow][schunk], Bt + (size_t)srow * ldb + kt + schunk);
        __syncthreads();
        bf16x8 a0 = *(const bf16x8*)(&As[wr      + lrow][koff]);
        bf16x8 a1 = *(const bf16x8*)(&As[wr + 16 + lrow][koff]);
        bf16x8 b0 = *(const bf16x8*)(&Bs[wc      + lrow][koff]);
        bf16x8 b1 = *(const bf16x8*)(&Bs[wc + 16 + lrow][koff]);
        acc[0][0] = __builtin_amdgcn_mfma_f32_16x16x32_bf16(a0, b0, acc[0][0], 0, 0, 0);
        acc[0][1] = __builtin_amdgcn_mfma_f32_16x16x32_bf16(a0, b1, acc[0][1], 0, 0, 0);
        acc[1][0] = __builtin_amdgcn_mfma_f32_16x16x32_bf16(a1, b0, acc[1][0], 0, 0, 0);
        acc[1][1] = __builtin_amdgcn_mfma_f32_16x16x32_bf16(a1, b1, acc[1][1], 0, 0, 0);
        __syncthreads();
    }
}

// ---------------------------------------------------------------------------
// Projection:  C[M x N] = A[M x K] * W[N x K]^T + bias.
// ---------------------------------------------------------------------------
template <typename TA, typename TC>
__global__ __launch_bounds__(256)
void k_proj(const TA* __restrict__ A, const float* __restrict__ W,
            const float* __restrict__ bias, TC* __restrict__ C, int K, int N)
{
    const int m0 = blockIdx.x * 64;
    const int n0 = blockIdx.y * 64;
    f32x4 z = {0.f, 0.f, 0.f, 0.f};
    f32x4 acc[2][2] = {{z, z}, {z, z}};
    gemm_core(A + (size_t)m0 * K, K, W + (size_t)n0 * K, K, K, acc);
    const int lane = threadIdx.x & 63;
    const int wave = threadIdx.x >> 6;
    const int wr = (wave >> 1) * 32, wc = (wave & 1) * 32;
#pragma unroll
    for (int i = 0; i < 2; ++i)
#pragma unroll
        for (int j = 0; j < 2; ++j) {
            const int col = n0 + wc + j * 16 + (lane & 15);
            const float bv = bias[col];
#pragma unroll
            for (int r = 0; r < 4; ++r) {
                const int row = m0 + wr + i * 16 + (lane >> 4) * 4 + r;
                store_one(&C[(size_t)row * N + col], acc[i][j][r] + bv);
            }
        }
}

// ---------------------------------------------------------------------------
// V projection with per-head transposed output: Vt[(b*H+h)*64 + d][k]  (bf16)
// ---------------------------------------------------------------------------
__global__ __launch_bounds__(256)
void k_projV(const float* __restrict__ A, const float* __restrict__ W,
             const float* __restrict__ bias, bf16* __restrict__ Vt)
{
    const int m0 = blockIdx.x * 64;
    const int n0 = blockIdx.y * 64;
    f32x4 z = {0.f, 0.f, 0.f, 0.f};
    f32x4 acc[2][2] = {{z, z}, {z, z}};
    gemm_core(A + (size_t)m0 * DMODEL, DMODEL, W + (size_t)n0 * DMODEL, DMODEL, DMODEL, acc);
    const int lane = threadIdx.x & 63;
    const int wave = threadIdx.x >> 6;
    const int wr = (wave >> 1) * 32, wc = (wave & 1) * 32;
#pragma unroll
    for (int i = 0; i < 2; ++i)
#pragma unroll
        for (int j = 0; j < 2; ++j) {
            const int col = n0 + wc + j * 16 + (lane & 15);
            const float bv = bias[col];
            const int h = col >> 6, d = col & 63;
            const int mb = m0 + wr + i * 16 + (lane >> 4) * 4;  // multiple of 4
            const int b = mb >> 11;
            const int kk = mb & 2047;
            bf16* dst = Vt + ((size_t)(b * NHEADS + h) * DHEAD + d) * SLK + kk;
#pragma unroll
            for (int r = 0; r < 4; ++r)
                dst[r] = __float2bfloat16(acc[i][j][r] + bv);
        }
}

// ---------------------------------------------------------------------------
// Fused attention: scores (+bias +mask) -> softmax -> attn write -> P·V.
// One block = one (b,h) head x 16 q-rows x full Lk=2048.
//   Phase A: qk*0.125 into S_lds (wave w owns cols [w*512, w*512+512))
//   Phase B: += bias, mask, flash (m,l) stats via shuffle reduce
//   Phase D: per 512-col chunk: p = exp(s-m)*inv -> attn (nontemporal f32)
//            and bf16 P chunk in LDS -> PV MFMA accumulate
//   ctx written into this block's own (dead) Qp slice.
// LDS: 131328 + 16640 + 640 = 148608 B  (<= 160 KiB/CU, 1 block/CU)
// ---------------------------------------------------------------------------
__global__ __launch_bounds__(256)
void k_attn(const bf16* __restrict__ Qp, const bf16* __restrict__ Kp,
            const float* __restrict__ bias, const int* __restrict__ mask,
            const bf16* __restrict__ Vt, float* __restrict__ attn,
            bf16* __restrict__ ctx)
{
    constexpr int SST = 2052;   // f32 stride: %32==4 -> 2-way (free) MFMA-epilogue writes
    constexpr int PST = 520;    // bf16 stride: 1040B, b128-aligned, 2-way reads

    __shared__ __align__(16) float S[16 * SST];
    __shared__ __align__(16) bf16  Pc[16 * PST];
    __shared__ float wmax[4][16], wsum[4][16];
    __shared__ float m_s[16], inv_s[16];

    const int qt = blockIdx.x, bh = blockIdx.y;
    const int b = bh >> 4, h = bh & 15;
    const int q0 = qt * 16;
    const int tid  = threadIdx.x;
    const int lane = tid & 63, w = tid >> 6;
    const int lr = lane & 15, lk = lane >> 4;

    // ---- Q fragments (rows q0..q0+15 of head h), K=64 -> two frags ----
    const bf16* qb = Qp + ((size_t)(b * SLQ + q0 + lr)) * DMODEL + h * DHEAD + lk * 8;
    const bf16x8 a0 = *(const bf16x8*)qb;
    const bf16x8 a1 = *(const bf16x8*)(qb + 32);

    // ---- Phase A: S = (Q.K^T) * 0.125 ----
    const bf16* kb = Kp + (size_t)b * SLK * DMODEL + h * DHEAD + lk * 8;
#pragma unroll 4
    for (int ct = 0; ct < 32; ++ct) {
        const int c0 = w * 512 + ct * 16;
        const bf16* kp = kb + (size_t)(c0 + lr) * DMODEL;
        bf16x8 b0 = *(const bf16x8*)kp;
        bf16x8 b1 = *(const bf16x8*)(kp + 32);
        f32x4 acc = {0.f, 0.f, 0.f, 0.f};
        acc = __builtin_amdgcn_mfma_f32_16x16x32_bf16(a0, b0, acc, 0, 0, 0);
        acc = __builtin_amdgcn_mfma_f32_16x16x32_bf16(a1, b1, acc, 0, 0, 0);
#pragma unroll
        for (int r = 0; r < 4; ++r)
            S[(lk * 4 + r) * SST + c0 + lr] = acc[r] * 0.125f;
    }

    // ---- Phase B: bias + mask, write back, flash stats (wave-local strip) ----
    for (int r = 0; r < 16; ++r) {
        float* sp = &S[r * SST + w * 512];
        const size_t brow = ((size_t)bh * SLQ + q0 + r) * SLK + w * 512 + lane * 4;
        const size_t mrow = ((size_t)b  * SLQ + q0 + r) * SLK + w * 512 + lane * 4;
        f32x4 v0 = *(const f32x4*)(sp + lane * 4);
        f32x4 v1 = *(const f32x4*)(sp + 256 + lane * 4);
        const float4 bb0 = *(const float4*)(bias + brow);
        const float4 bb1 = *(const float4*)(bias + brow + 256);
        const int4 mm0 = *(const int4*)(mask + mrow);
        const int4 mm1 = *(const int4*)(mask + mrow + 256);
        float s0 = (mm0.x == 0) ? -1e9f : v0[0] + bb0.x;
        float s1 = (mm0.y == 0) ? -1e9f : v0[1] + bb0.y;
        float s2 = (mm0.z == 0) ? -1e9f : v0[2] + bb0.z;
        float s3 = (mm0.w == 0) ? -1e9f : v0[3] + bb0.w;
        float s4 = (mm1.x == 0) ? -1e9f : v1[0] + bb1.x;
        float s5 = (mm1.y == 0) ? -1e9f : v1[1] + bb1.y;
        float s6 = (mm1.z == 0) ? -1e9f : v1[2] + bb1.z;
        float s7 = (mm1.w == 0) ? -1e9f : v1[3] + bb1.w;
        f32x4 w0 = {s0, s1, s2, s3};
        f32x4 w1 = {s4, s5, s6, s7};
        *(f32x4*)(sp + lane * 4)       = w0;
        *(f32x4*)(sp + 256 + lane * 4) = w1;

        float mx = fmaxf(fmaxf(fmaxf(s0, s1), fmaxf(s2, s3)),
                         fmaxf(fmaxf(s4, s5), fmaxf(s6, s7)));
        float l = __expf(s0 - mx) + __expf(s1 - mx) + __expf(s2 - mx) + __expf(s3 - mx)
                + __expf(s4 - mx) + __expf(s5 - mx) + __expf(s6 - mx) + __expf(s7 - mx);
        float mw = mx;
#pragma unroll
        for (int d = 1; d < 64; d <<= 1) mw = fmaxf(mw, __shfl_xor(mw, d));
        float lw = l * __expf(mx - mw);
#pragma unroll
        for (int d = 1; d < 64; d <<= 1) lw += __shfl_xor(lw, d);
        if (lane == 0) { wmax[w][r] = mw; wsum[w][r] = lw; }
    }
    __syncthreads();
    if (tid < 16) {
        const float m = fmaxf(fmaxf(wmax[0][tid], wmax[1][tid]),
                              fmaxf(wmax[2][tid], wmax[3][tid]));
        const float l = wsum[0][tid] * __expf(wmax[0][tid] - m)
                      + wsum[1][tid] * __expf(wmax[1][tid] - m)
                      + wsum[2][tid] * __expf(wmax[2][tid] - m)
                      + wsum[3][tid] * __expf(wmax[3][tid] - m);
        m_s[tid]   = m;
        inv_s[tid] = 1.0f / l;
    }
    __syncthreads();

    // ---- Phase D: per 512-col chunk: attn write + bf16 P -> PV MFMA ----
    f32x4 pv = {0.f, 0.f, 0.f, 0.f};
    const bf16* vb = Vt + (size_t)bh * DHEAD * SLK + (size_t)(w * 16 + lr) * SLK + lk * 8;
    const int trow = tid >> 7;            // 0/1: row parity
    const int tcol = (tid & 127) * 4;     // col within chunk
    for (int c = 0; c < 4; ++c) {
        const int ck0 = c * 512;
#pragma unroll
        for (int rp = 0; rp < 8; ++rp) {
            const int row = rp * 2 + trow;
            const f32x4 sv = *(const f32x4*)&S[row * SST + ck0 + tcol];
            const float m = m_s[row], inv = inv_s[row];
            const float p0 = __expf(sv[0] - m) * inv;
            const float p1 = __expf(sv[1] - m) * inv;
            const float p2 = __expf(sv[2] - m) * inv;
            const float p3 = __expf(sv[3] - m) * inv;
            const f32x4 pf = {p0, p1, p2, p3};
            __builtin_nontemporal_store(pf,
                (f32x4*)(attn + ((size_t)bh * SLQ + q0 + row) * SLK + ck0 + tcol));
            bf16 t4[4] = {__float2bfloat16(p0), __float2bfloat16(p1),
                          __float2bfloat16(p2), __float2bfloat16(p3)};
            *(int2*)&Pc[row * PST + tcol] = *(const int2*)t4;
        }
        __syncthreads();
        const bf16* vc = vb + ck0;
#pragma unroll
        for (int ks = 0; ks < 16; ++ks) {
            bf16x8 pa = *(const bf16x8*)&Pc[lr * PST + ks * 32 + lk * 8];
            bf16x8 vv = *(const bf16x8*)(vc + ks * 32);
            pv = __builtin_amdgcn_mfma_f32_16x16x32_bf16(pa, vv, pv, 0, 0, 0);
        }
        __syncthreads();
    }

    // ---- ctx write: exactly this block's Qp slice (safe in-kernel alias) ----
    const int d = w * 16 + lr;
#pragma unroll
    for (int r = 0; r < 4; ++r) {
        const int q = lk * 4 + r;
        ctx[((size_t)(b * SLQ + q0 + q)) * DMODEL + h * DHEAD + d] =
            __float2bfloat16(pv[r]);
    }
}

// ---------------------------------------------------------------------------
// Layout (all global I/O f32; intermediates bf16):
//   d_out: out f32 [0 .. 8MB) ‖ attn f32 [8MB .. 276MB)
//   Kp  = d_out[0 .. 8MB) bf16   live: projK -> k_attn (dead before final out)
//   Qp  = ws[0 .. 4MB)  bf16     live: projQ -> k_attn phase A
//   ctx = ws[0 .. 4MB)  bf16     aliases Qp per-block exact slices (k_attn epi)
//   Vt  = ws[8 .. 16MB) bf16     live: projV -> k_attn PV
// Final proj reads ctx (ws) and writes out (d_out, dead Kp) -> no race.
// Peak ws = 16 MB.
// ---------------------------------------------------------------------------
extern "C" void kernel_launch(void* const* d_in, const int* in_sizes, int n_in,
                              void* d_out, int out_size, void* d_ws, size_t ws_size,
                              hipStream_t stream)
{
    const float* query = (const float*)d_in[0];
    const float* key   = (const float*)d_in[1];
    const float* value = (const float*)d_in[2];
    const int*   mask  = (const int*)d_in[3];
    const float* bias  = (const float*)d_in[4];
    const float* Wq = (const float*)d_in[5];
    const float* bq = (const float*)d_in[6];
    const float* Wk = (const float*)d_in[7];
    const float* bk = (const float*)d_in[8];
    const float* Wv = (const float*)d_in[9];
    const float* bv = (const float*)d_in[10];
    const float* Wo = (const float*)d_in[11];
    const float* bo = (const float*)d_in[12];

    float* out  = (float*)d_out;            // [B, Lq, D] f32
    float* attn = out + OUTQ;               // [B, H, Lq, Lk] f32

    bf16* Qp  = (bf16*)d_ws;                          // ws[0..4MB)
    bf16* ctx = (bf16*)d_ws;                          // aliases Qp (in-kernel exact slices)
    bf16* Kp  = (bf16*)d_out;                         // borrows out region [0..8MB)
    bf16* Vt  = (bf16*)d_ws + (size_t)4 * 1024 * 1024; // ws[8..16MB)

    dim3 blk(256);

    k_proj<float, bf16><<<dim3(BATCH * SLQ / 64, DMODEL / 64), blk, 0, stream>>>(query, Wq, bq, Qp, DMODEL, DMODEL);
    k_proj<float, bf16><<<dim3(BATCH * SLK / 64, DMODEL / 64), blk, 0, stream>>>(key,   Wk, bk, Kp, DMODEL, DMODEL);
    k_projV<<<dim3(BATCH * SLK / 64, DMODEL / 64), blk, 0, stream>>>(value, Wv, bv, Vt);
    k_attn<<<dim3(SLQ / 16, BATCH * NHEADS), blk, 0, stream>>>(Qp, Kp, bias, mask, Vt, attn, ctx);
    k_proj<bf16, float><<<dim3(BATCH * SLQ / 64, DMODEL / 64), blk, 0, stream>>>(ctx, Wo, bo, out, DMODEL, DMODEL);
}

// Round 4
// 740.400 us; speedup vs baseline: 1.2013x; 1.1123x over previous
//
#include <hip/hip_runtime.h>
#include <hip/hip_bf16.h>

typedef __hip_bfloat16 bf16;
typedef __bf16  bf16x8 __attribute__((ext_vector_type(8)));
typedef float   f32x4  __attribute__((ext_vector_type(4)));

static constexpr int DMODEL = 1024;
static constexpr int NHEADS = 16;
static constexpr int DHEAD  = 64;
static constexpr int BATCH  = 2;
static constexpr int SLQ    = 1024;
static constexpr int SLK    = 2048;
static constexpr size_t OUTQ = (size_t)BATCH * SLQ * DMODEL;   // out elems (f32)

// ---------------------------------------------------------------------------
// Stage 8 contiguous elements into LDS as bf16 (converting if source is f32).
// ---------------------------------------------------------------------------
__device__ __forceinline__ void stage8(unsigned short* dst, const bf16* src) {
    *(int4*)dst = *(const int4*)src;
}
__device__ __forceinline__ void stage8(unsigned short* dst, const float* src) {
    const float4 a = *(const float4*)(src);
    const float4 b = *(const float4*)(src + 4);
    bf16 h[8];
    h[0] = __float2bfloat16(a.x); h[1] = __float2bfloat16(a.y);
    h[2] = __float2bfloat16(a.z); h[3] = __float2bfloat16(a.w);
    h[4] = __float2bfloat16(b.x); h[5] = __float2bfloat16(b.y);
    h[6] = __float2bfloat16(b.z); h[7] = __float2bfloat16(b.w);
    *(int4*)dst = *(const int4*)h;
}

__device__ __forceinline__ void store_one(bf16* p, float v) { *p = __float2bfloat16(v); }
__device__ __forceinline__ void store_one(float* p, float v) { *p = v; }

// ---------------------------------------------------------------------------
// Core 64x64 tile GEMM:  C_tile = A_tile (64 x K) * B_tile^T (K x 64)
// 256 threads = 4 waves in 2x2; each wave a 32x32 sub-tile via 2x2
// v_mfma_f32_16x16x32_bf16.
// ---------------------------------------------------------------------------
template <typename TA, typename TB>
__device__ __forceinline__ void gemm_core(const TA* __restrict__ At, int lda,
                                          const TB* __restrict__ Bt, int ldb,
                                          int K, f32x4 acc[2][2])
{
    __shared__ __align__(16) unsigned short As[64][40];
    __shared__ __align__(16) unsigned short Bs[64][40];
    const int tid  = threadIdx.x;
    const int lane = tid & 63;
    const int wave = tid >> 6;
    const int wr   = (wave >> 1) * 32;
    const int wc   = (wave & 1) * 32;
    const int lrow = lane & 15;
    const int koff = (lane >> 4) * 8;
    const int srow   = tid >> 2;
    const int schunk = (tid & 3) * 8;

    for (int kt = 0; kt < K; kt += 32) {
        stage8(&As[srow][schunk], At + (size_t)srow * lda + kt + schunk);
        stage8(&Bs[srow][schunk], Bt + (size_t)srow * ldb + kt + schunk);
        __syncthreads();
        bf16x8 a0 = *(const bf16x8*)(&As[wr      + lrow][koff]);
        bf16x8 a1 = *(const bf16x8*)(&As[wr + 16 + lrow][koff]);
        bf16x8 b0 = *(const bf16x8*)(&Bs[wc      + lrow][koff]);
        bf16x8 b1 = *(const bf16x8*)(&Bs[wc + 16 + lrow][koff]);
        acc[0][0] = __builtin_amdgcn_mfma_f32_16x16x32_bf16(a0, b0, acc[0][0], 0, 0, 0);
        acc[0][1] = __builtin_amdgcn_mfma_f32_16x16x32_bf16(a0, b1, acc[0][1], 0, 0, 0);
        acc[1][0] = __builtin_amdgcn_mfma_f32_16x16x32_bf16(a1, b0, acc[1][0], 0, 0, 0);
        acc[1][1] = __builtin_amdgcn_mfma_f32_16x16x32_bf16(a1, b1, acc[1][1], 0, 0, 0);
        __syncthreads();
    }
}

// ---------------------------------------------------------------------------
// Projection:  C[M x N] = A[M x K] * W[N x K]^T + bias.
// ---------------------------------------------------------------------------
template <typename TA, typename TC>
__global__ __launch_bounds__(256)
void k_proj(const TA* __restrict__ A, const float* __restrict__ W,
            const float* __restrict__ bias, TC* __restrict__ C, int K, int N)
{
    const int m0 = blockIdx.x * 64;
    const int n0 = blockIdx.y * 64;
    f32x4 z = {0.f, 0.f, 0.f, 0.f};
    f32x4 acc[2][2] = {{z, z}, {z, z}};
    gemm_core(A + (size_t)m0 * K, K, W + (size_t)n0 * K, K, K, acc);
    const int lane = threadIdx.x & 63;
    const int wave = threadIdx.x >> 6;
    const int wr = (wave >> 1) * 32, wc = (wave & 1) * 32;
#pragma unroll
    for (int i = 0; i < 2; ++i)
#pragma unroll
        for (int j = 0; j < 2; ++j) {
            const int col = n0 + wc + j * 16 + (lane & 15);
            const float bv = bias[col];
#pragma unroll
            for (int r = 0; r < 4; ++r) {
                const int row = m0 + wr + i * 16 + (lane >> 4) * 4 + r;
                store_one(&C[(size_t)row * N + col], acc[i][j][r] + bv);
            }
        }
}

// ---------------------------------------------------------------------------
// V projection with per-head transposed output: Vt[(b*H+h)*64 + d][k]  (bf16)
// ---------------------------------------------------------------------------
__global__ __launch_bounds__(256)
void k_projV(const float* __restrict__ A, const float* __restrict__ W,
             const float* __restrict__ bias, bf16* __restrict__ Vt)
{
    const int m0 = blockIdx.x * 64;
    const int n0 = blockIdx.y * 64;
    f32x4 z = {0.f, 0.f, 0.f, 0.f};
    f32x4 acc[2][2] = {{z, z}, {z, z}};
    gemm_core(A + (size_t)m0 * DMODEL, DMODEL, W + (size_t)n0 * DMODEL, DMODEL, DMODEL, acc);
    const int lane = threadIdx.x & 63;
    const int wave = threadIdx.x >> 6;
    const int wr = (wave >> 1) * 32, wc = (wave & 1) * 32;
#pragma unroll
    for (int i = 0; i < 2; ++i)
#pragma unroll
        for (int j = 0; j < 2; ++j) {
            const int col = n0 + wc + j * 16 + (lane & 15);
            const float bv = bias[col];
            const int h = col >> 6, d = col & 63;
            const int mb = m0 + wr + i * 16 + (lane >> 4) * 4;  // multiple of 4
            const int b = mb >> 11;
            const int kk = mb & 2047;
            bf16* dst = Vt + ((size_t)(b * NHEADS + h) * DHEAD + d) * SLK + kk;
#pragma unroll
            for (int r = 0; r < 4; ++r)
                dst[r] = __float2bfloat16(acc[i][j][r] + bv);
        }
}

// ---------------------------------------------------------------------------
// Fused attention: scores (+bias +mask) -> softmax -> attn write -> P·V.
// One block = one (b,h) head x 16 q-rows x full Lk=2048.  1024 thr = 16 waves
// (the round-2 fix: occupancy 4 -> 16 waves/CU at the same 148KB LDS).
//   Phase A: wave w computes cols [w*128, w*128+128) of S = QK^T * 0.125
//   Phase B: wave w owns q-row w entirely: bias+mask+writeback, row max/sum
//            via wave-level shuffle reduce only
//   Phase D: per 512-col chunk: wave w = (kgroup g=w>>2, dgroup dg=w&3)
//            p=exp(s-m)*inv -> attn (nontemporal) + bf16 Pc; 4 MFMA per wave;
//            final 4-way k-group reduction staged through dead S buffer.
// LDS: 131328 (S) + 16640 (Pc) + 128 = 148096 B  (1 block/CU, 16 waves)
// ---------------------------------------------------------------------------
__global__ __launch_bounds__(1024, 4)
void k_attn(const bf16* __restrict__ Qp, const bf16* __restrict__ Kp,
            const float* __restrict__ bias, const int* __restrict__ mask,
            const bf16* __restrict__ Vt, float* __restrict__ attn,
            bf16* __restrict__ ctx)
{
    constexpr int SST = 2052;   // f32 stride
    constexpr int PST = 520;    // bf16 stride

    __shared__ __align__(16) float S[16 * SST];
    __shared__ __align__(16) bf16  Pc[16 * PST];
    __shared__ float m_s[16], inv_s[16];

    const int qt = blockIdx.x, bh = blockIdx.y;
    const int b = bh >> 4, h = bh & 15;
    const int q0 = qt * 16;
    const int tid  = threadIdx.x;
    const int lane = tid & 63, w = tid >> 6;
    const int lr = lane & 15, lk = lane >> 4;

    // ---- Q fragments (rows q0..q0+15 of head h), K=64 -> two frags ----
    const bf16* qb = Qp + ((size_t)(b * SLQ + q0 + lr)) * DMODEL + h * DHEAD + lk * 8;
    const bf16x8 a0 = *(const bf16x8*)qb;
    const bf16x8 a1 = *(const bf16x8*)(qb + 32);

    // ---- Phase A: S = (Q.K^T) * 0.125  (wave w: 128-col strip) ----
    const bf16* kb = Kp + (size_t)b * SLK * DMODEL + h * DHEAD + lk * 8;
#pragma unroll 2
    for (int ct = 0; ct < 8; ++ct) {
        const int c0 = w * 128 + ct * 16;
        const bf16* kp = kb + (size_t)(c0 + lr) * DMODEL;
        bf16x8 b0 = *(const bf16x8*)kp;
        bf16x8 b1 = *(const bf16x8*)(kp + 32);
        f32x4 acc = {0.f, 0.f, 0.f, 0.f};
        acc = __builtin_amdgcn_mfma_f32_16x16x32_bf16(a0, b0, acc, 0, 0, 0);
        acc = __builtin_amdgcn_mfma_f32_16x16x32_bf16(a1, b1, acc, 0, 0, 0);
#pragma unroll
        for (int r = 0; r < 4; ++r)
            S[(lk * 4 + r) * SST + c0 + lr] = acc[r] * 0.125f;
    }
    __syncthreads();

    // ---- Phase B: wave w owns q-row w: bias + mask + stats ----
    {
        float* sp = &S[w * SST];
        const size_t brow = ((size_t)bh * SLQ + q0 + w) * SLK;
        const size_t mrow = ((size_t)b  * SLQ + q0 + w) * SLK;
        float mx = -3.0e38f;
#pragma unroll 2
        for (int j = 0; j < 8; ++j) {
            const int col = j * 256 + lane * 4;
            f32x4 v = *(const f32x4*)(sp + col);
            const float4 bb = *(const float4*)(bias + brow + col);
            const int4  mm = *(const int4*)(mask + mrow + col);
            float s0 = (mm.x == 0) ? -1e9f : v[0] + bb.x;
            float s1 = (mm.y == 0) ? -1e9f : v[1] + bb.y;
            float s2 = (mm.z == 0) ? -1e9f : v[2] + bb.z;
            float s3 = (mm.w == 0) ? -1e9f : v[3] + bb.w;
            f32x4 wv = {s0, s1, s2, s3};
            *(f32x4*)(sp + col) = wv;
            mx = fmaxf(mx, fmaxf(fmaxf(s0, s1), fmaxf(s2, s3)));
        }
#pragma unroll
        for (int d = 1; d < 64; d <<= 1) mx = fmaxf(mx, __shfl_xor(mx, d));
        float l = 0.f;
#pragma unroll 2
        for (int j = 0; j < 8; ++j) {
            const int col = j * 256 + lane * 4;
            const f32x4 v = *(const f32x4*)(sp + col);
            l += __expf(v[0] - mx) + __expf(v[1] - mx)
               + __expf(v[2] - mx) + __expf(v[3] - mx);
        }
#pragma unroll
        for (int d = 1; d < 64; d <<= 1) l += __shfl_xor(l, d);
        if (lane == 0) { m_s[w] = mx; inv_s[w] = 1.0f / l; }
    }
    __syncthreads();

    // ---- Phase D: per 512-col chunk: attn write + bf16 P -> PV MFMA ----
    f32x4 pv = {0.f, 0.f, 0.f, 0.f};
    const int g = w >> 2, dg = w & 3;
    const bf16* vb = Vt + (size_t)bh * DHEAD * SLK + (size_t)(dg * 16 + lr) * SLK + lk * 8;
    for (int c = 0; c < 4; ++c) {
        const int ck0 = c * 512;
        {   // row w, cols lane*8..lane*8+7 of this chunk
            const int scol = lane * 8;
            const float m = m_s[w], inv = inv_s[w];
            const f32x4 s0 = *(const f32x4*)&S[w * SST + ck0 + scol];
            const f32x4 s1 = *(const f32x4*)&S[w * SST + ck0 + scol + 4];
            const f32x4 p0 = {__expf(s0[0] - m) * inv, __expf(s0[1] - m) * inv,
                              __expf(s0[2] - m) * inv, __expf(s0[3] - m) * inv};
            const f32x4 p1 = {__expf(s1[0] - m) * inv, __expf(s1[1] - m) * inv,
                              __expf(s1[2] - m) * inv, __expf(s1[3] - m) * inv};
            float* ap = attn + ((size_t)bh * SLQ + q0 + w) * SLK + ck0 + scol;
            __builtin_nontemporal_store(p0, (f32x4*)ap);
            __builtin_nontemporal_store(p1, (f32x4*)(ap + 4));
            bf16 t8[8] = {__float2bfloat16(p0[0]), __float2bfloat16(p0[1]),
                          __float2bfloat16(p0[2]), __float2bfloat16(p0[3]),
                          __float2bfloat16(p1[0]), __float2bfloat16(p1[1]),
                          __float2bfloat16(p1[2]), __float2bfloat16(p1[3])};
            *(int4*)&Pc[w * PST + scol] = *(const int4*)t8;
        }
        __syncthreads();
        const bf16* vc = vb + ck0;
#pragma unroll
        for (int i = 0; i < 4; ++i) {
            const int koff = (g * 4 + i) * 32;
            bf16x8 pa = *(const bf16x8*)&Pc[lr * PST + koff + lk * 8];
            bf16x8 vv = *(const bf16x8*)(vc + koff);
            pv = __builtin_amdgcn_mfma_f32_16x16x32_bf16(pa, vv, pv, 0, 0, 0);
        }
        __syncthreads();
    }

    // ---- 4-way k-group reduction through dead S buffer, then ctx write ----
    float* rbuf = S;   // S is dead; 16KB staging
    *(f32x4*)&rbuf[(w * 64 + lane) * 4] = pv;
    __syncthreads();
    if (g == 0) {
        f32x4 t = {0.f, 0.f, 0.f, 0.f};
#pragma unroll
        for (int gg = 0; gg < 4; ++gg)
            t += *(const f32x4*)&rbuf[((gg * 4 + dg) * 64 + lane) * 4];
        const int d = dg * 16 + lr;
#pragma unroll
        for (int r = 0; r < 4; ++r) {
            const int q = lk * 4 + r;
            ctx[((size_t)(b * SLQ + q0 + q)) * DMODEL + h * DHEAD + d] =
                __float2bfloat16(t[r]);
        }
    }
}

// ---------------------------------------------------------------------------
// Layout (all global I/O f32; intermediates bf16):
//   d_out: out f32 [0 .. 8MB) ‖ attn f32 [8MB .. 276MB)
//   Kp  = d_out[0 .. 8MB) bf16   live: projK -> k_attn (dead before final out)
//   Qp  = ws[0 .. 4MB)  bf16     live: projQ -> k_attn phase A
//   ctx = ws[0 .. 4MB)  bf16     aliases Qp per-block exact slices (k_attn epi)
//   Vt  = ws[8 .. 16MB) bf16     live: projV -> k_attn PV
// Final proj reads ctx (ws) and writes out (d_out, dead Kp) -> no race.
// Peak ws = 16 MB.
// ---------------------------------------------------------------------------
extern "C" void kernel_launch(void* const* d_in, const int* in_sizes, int n_in,
                              void* d_out, int out_size, void* d_ws, size_t ws_size,
                              hipStream_t stream)
{
    const float* query = (const float*)d_in[0];
    const float* key   = (const float*)d_in[1];
    const float* value = (const float*)d_in[2];
    const int*   mask  = (const int*)d_in[3];
    const float* bias  = (const float*)d_in[4];
    const float* Wq = (const float*)d_in[5];
    const float* bq = (const float*)d_in[6];
    const float* Wk = (const float*)d_in[7];
    const float* bk = (const float*)d_in[8];
    const float* Wv = (const float*)d_in[9];
    const float* bv = (const float*)d_in[10];
    const float* Wo = (const float*)d_in[11];
    const float* bo = (const float*)d_in[12];

    float* out  = (float*)d_out;            // [B, Lq, D] f32
    float* attn = out + OUTQ;               // [B, H, Lq, Lk] f32

    bf16* Qp  = (bf16*)d_ws;                          // ws[0..4MB)
    bf16* ctx = (bf16*)d_ws;                          // aliases Qp (in-kernel exact slices)
    bf16* Kp  = (bf16*)d_out;                         // borrows out region [0..8MB)
    bf16* Vt  = (bf16*)d_ws + (size_t)4 * 1024 * 1024; // ws[8..16MB)

    dim3 blk(256);

    k_proj<float, bf16><<<dim3(BATCH * SLQ / 64, DMODEL / 64), blk, 0, stream>>>(query, Wq, bq, Qp, DMODEL, DMODEL);
    k_proj<float, bf16><<<dim3(BATCH * SLK / 64, DMODEL / 64), blk, 0, stream>>>(key,   Wk, bk, Kp, DMODEL, DMODEL);
    k_projV<<<dim3(BATCH * SLK / 64, DMODEL / 64), blk, 0, stream>>>(value, Wv, bv, Vt);
    k_attn<<<dim3(SLQ / 16, BATCH * NHEADS), dim3(1024), 0, stream>>>(Qp, Kp, bias, mask, Vt, attn, ctx);
    k_proj<bf16, float><<<dim3(BATCH * SLQ / 64, DMODEL / 64), blk, 0, stream>>>(ctx, Wo, bo, out, DMODEL, DMODEL);
}

// Round 5
// 708.232 us; speedup vs baseline: 1.2559x; 1.0454x over previous
//
#include <hip/hip_runtime.h>
#include <hip/hip_bf16.h>

typedef __hip_bfloat16 bf16;
typedef __bf16  bf16x8 __attribute__((ext_vector_type(8)));
typedef float   f32x4  __attribute__((ext_vector_type(4)));

static constexpr int DMODEL = 1024;
static constexpr int NHEADS = 16;
static constexpr int DHEAD  = 64;
static constexpr int BATCH  = 2;
static constexpr int SLQ    = 1024;
static constexpr int SLK    = 2048;
static constexpr size_t OUTQ = (size_t)BATCH * SLQ * DMODEL;   // out elems (f32)

// ---------------------------------------------------------------------------
// k_cvt: one-shot f32 -> bf16 conversion of q/k/v inputs + 4 weight matrices.
// grid = (256, 7); seg = blockIdx.y picks the array.
// ---------------------------------------------------------------------------
__global__ __launch_bounds__(256)
void k_cvt(const float* __restrict__ q,  const float* __restrict__ k,
           const float* __restrict__ v,  const float* __restrict__ wq,
           const float* __restrict__ wk, const float* __restrict__ wv,
           const float* __restrict__ wo,
           bf16* __restrict__ qb,  bf16* __restrict__ kb,  bf16* __restrict__ vb,
           bf16* __restrict__ wqb, bf16* __restrict__ wkb, bf16* __restrict__ wvb,
           bf16* __restrict__ wob)
{
    const int seg = blockIdx.y;
    const float* s; bf16* d; int n;
    switch (seg) {
        case 0:  s = q;  d = qb;  n = 2 * 1024 * 1024; break;
        case 1:  s = k;  d = kb;  n = 4 * 1024 * 1024; break;
        case 2:  s = v;  d = vb;  n = 4 * 1024 * 1024; break;
        case 3:  s = wq; d = wqb; n = 1024 * 1024; break;
        case 4:  s = wk; d = wkb; n = 1024 * 1024; break;
        case 5:  s = wv; d = wvb; n = 1024 * 1024; break;
        default: s = wo; d = wob; n = 1024 * 1024; break;
    }
    const int stride = gridDim.x * blockDim.x;
    for (int i = blockIdx.x * blockDim.x + threadIdx.x; i * 8 < n; i += stride) {
        const float4 a = *(const float4*)(s + (size_t)i * 8);
        const float4 b = *(const float4*)(s + (size_t)i * 8 + 4);
        bf16 h[8] = {__float2bfloat16(a.x), __float2bfloat16(a.y),
                     __float2bfloat16(a.z), __float2bfloat16(a.w),
                     __float2bfloat16(b.x), __float2bfloat16(b.y),
                     __float2bfloat16(b.z), __float2bfloat16(b.w)};
        *(int4*)(d + (size_t)i * 8) = *(const int4*)h;
    }
}

// ---------------------------------------------------------------------------
// 128x128-tile bf16 GEMM core (m93 structure): C_tile = A(128xK) * W(128xK)^T
// 256 thr = 4 waves in 2x2, each wave 64x64 via acc[4][4] of 16x16x32 MFMA.
// LDS [128][40] padded (row stride 80B = 5x16B: b128-aligned, 2-way conflicts).
// A/B frag: elem[m=lane&15][k=(lane>>4)*8+j]; C/D: col=lane&15,row=(lane>>4)*4+r
// ---------------------------------------------------------------------------
__device__ __forceinline__ void gemm128(const bf16* __restrict__ A,
                                        const bf16* __restrict__ W,
                                        int m0, int n0, f32x4 acc[4][4])
{
    __shared__ __align__(16) unsigned short As[128][40];
    __shared__ __align__(16) unsigned short Bs[128][40];
    const int tid  = threadIdx.x;
    const int lane = tid & 63, w = tid >> 6;
    const int wr = (w >> 1) * 64, wc = (w & 1) * 64;
    const int lr = lane & 15, lk = lane >> 4;
    const int srow = tid >> 1;          // 0..127
    const int scol = (tid & 1) * 16;    // 0 / 16

    const bf16* Ap = A + (size_t)(m0 + srow) * DMODEL + scol;
    const bf16* Wp = W + (size_t)(n0 + srow) * DMODEL + scol;

    for (int kt = 0; kt < DMODEL; kt += 32) {
        *(int4*)&As[srow][scol]     = *(const int4*)(Ap + kt);
        *(int4*)&As[srow][scol + 8] = *(const int4*)(Ap + kt + 8);
        *(int4*)&Bs[srow][scol]     = *(const int4*)(Wp + kt);
        *(int4*)&Bs[srow][scol + 8] = *(const int4*)(Wp + kt + 8);
        __syncthreads();
        bf16x8 av[4], wv[4];
#pragma unroll
        for (int i = 0; i < 4; ++i)
            av[i] = *(const bf16x8*)&As[wr + i * 16 + lr][lk * 8];
#pragma unroll
        for (int j = 0; j < 4; ++j)
            wv[j] = *(const bf16x8*)&Bs[wc + j * 16 + lr][lk * 8];
#pragma unroll
        for (int i = 0; i < 4; ++i)
#pragma unroll
            for (int j = 0; j < 4; ++j)
                acc[i][j] = __builtin_amdgcn_mfma_f32_16x16x32_bf16(av[i], wv[j], acc[i][j], 0, 0, 0);
        __syncthreads();
    }
}

// ---------------------------------------------------------------------------
// Fused Q/K/V projections: blockIdx.z = which (0:Q, 1:K, 2:V-transposed).
// grid = (32, 8, 3); Q blocks with m0 >= 2048 exit early.
// ---------------------------------------------------------------------------
__global__ __launch_bounds__(256)
void k_qkv(const bf16* __restrict__ qb, const bf16* __restrict__ kb,
           const bf16* __restrict__ vb2,
           const bf16* __restrict__ wqb, const bf16* __restrict__ wkb,
           const bf16* __restrict__ wvb,
           const float* __restrict__ bq, const float* __restrict__ bk,
           const float* __restrict__ bvv,
           bf16* __restrict__ Qp, bf16* __restrict__ Kp, bf16* __restrict__ Vt)
{
    const int which = blockIdx.z;
    const int m0 = blockIdx.x * 128, n0 = blockIdx.y * 128;
    if (which == 0 && m0 >= BATCH * SLQ) return;
    const bf16* A = which == 0 ? qb : which == 1 ? kb : vb2;
    const bf16* W = which == 0 ? wqb : which == 1 ? wkb : wvb;
    const float* bias = which == 0 ? bq : which == 1 ? bk : bvv;

    f32x4 acc[4][4] = {};
    gemm128(A, W, m0, n0, acc);

    const int tid = threadIdx.x, lane = tid & 63, w = tid >> 6;
    const int wr = (w >> 1) * 64, wc = (w & 1) * 64;
    const int lr = lane & 15, lk = lane >> 4;

    if (which < 2) {
        bf16* C = which == 0 ? Qp : Kp;
#pragma unroll
        for (int i = 0; i < 4; ++i)
#pragma unroll
            for (int j = 0; j < 4; ++j) {
                const int col = n0 + wc + j * 16 + lr;
                const float bvx = bias[col];
#pragma unroll
                for (int r = 0; r < 4; ++r) {
                    const int row = m0 + wr + i * 16 + lk * 4 + r;
                    C[(size_t)row * DMODEL + col] = __float2bfloat16(acc[i][j][r] + bvx);
                }
            }
    } else {
#pragma unroll
        for (int i = 0; i < 4; ++i)
#pragma unroll
            for (int j = 0; j < 4; ++j) {
                const int col = n0 + wc + j * 16 + lr;
                const float bvx = bias[col];
                const int h = col >> 6, d = col & 63;
                const int mb = m0 + wr + i * 16 + lk * 4;   // multiple of 4
                const int b = mb >> 11, kk = mb & 2047;
                bf16* dst = Vt + ((size_t)(b * NHEADS + h) * DHEAD + d) * SLK + kk;
#pragma unroll
                for (int r = 0; r < 4; ++r)
                    dst[r] = __float2bfloat16(acc[i][j][r] + bvx);
            }
    }
}

// ---------------------------------------------------------------------------
// Output projection: out[2048x1024] f32 = ctx(bf16) * Wo^T + bo.  grid (16,8).
// ---------------------------------------------------------------------------
__global__ __launch_bounds__(256)
void k_projO(const bf16* __restrict__ ctx, const bf16* __restrict__ wob,
             const float* __restrict__ bo, float* __restrict__ out)
{
    const int m0 = blockIdx.x * 128, n0 = blockIdx.y * 128;
    f32x4 acc[4][4] = {};
    gemm128(ctx, wob, m0, n0, acc);
    const int tid = threadIdx.x, lane = tid & 63, w = tid >> 6;
    const int wr = (w >> 1) * 64, wc = (w & 1) * 64;
    const int lr = lane & 15, lk = lane >> 4;
#pragma unroll
    for (int i = 0; i < 4; ++i)
#pragma unroll
        for (int j = 0; j < 4; ++j) {
            const int col = n0 + wc + j * 16 + lr;
            const float bvx = bo[col];
#pragma unroll
            for (int r = 0; r < 4; ++r) {
                const int row = m0 + wr + i * 16 + lk * 4 + r;
                out[(size_t)row * DMODEL + col] = acc[i][j][r] + bvx;
            }
        }
}

// ---------------------------------------------------------------------------
// Fused attention: scores (+bias +mask) -> softmax -> attn write -> P·V.
// One block = one (b,h) head x 16 q-rows x full Lk=2048.  1024 thr = 16 waves.
//   Phase A: wave w computes cols [w*128, w*128+128) of S = QK^T * 0.125
//   Phase B: wave w owns q-row w: bias+mask+writeback, shuffle-reduce stats
//   Phase D: per 512-col chunk: wave w = (kgroup g=w>>2, dgroup dg=w&3)
//            p=exp(s-m)*inv -> attn (nontemporal) + bf16 Pc; 4 MFMA per wave;
//            final 4-way k-group reduction staged through dead S buffer.
// LDS: 131328 (S) + 16640 (Pc) + 128 = 148096 B  (1 block/CU, 16 waves)
// ---------------------------------------------------------------------------
__global__ __launch_bounds__(1024, 4)
void k_attn(const bf16* __restrict__ Qp, const bf16* __restrict__ Kp,
            const float* __restrict__ bias, const int* __restrict__ mask,
            const bf16* __restrict__ Vt, float* __restrict__ attn,
            bf16* __restrict__ ctx)
{
    constexpr int SST = 2052;   // f32 stride
    constexpr int PST = 520;    // bf16 stride

    __shared__ __align__(16) float S[16 * SST];
    __shared__ __align__(16) bf16  Pc[16 * PST];
    __shared__ float m_s[16], inv_s[16];

    const int qt = blockIdx.x, bh = blockIdx.y;
    const int b = bh >> 4, h = bh & 15;
    const int q0 = qt * 16;
    const int tid  = threadIdx.x;
    const int lane = tid & 63, w = tid >> 6;
    const int lr = lane & 15, lk = lane >> 4;

    // ---- Q fragments (rows q0..q0+15 of head h), K=64 -> two frags ----
    const bf16* qb = Qp + ((size_t)(b * SLQ + q0 + lr)) * DMODEL + h * DHEAD + lk * 8;
    const bf16x8 a0 = *(const bf16x8*)qb;
    const bf16x8 a1 = *(const bf16x8*)(qb + 32);

    // ---- Phase A: S = (Q.K^T) * 0.125  (wave w: 128-col strip) ----
    const bf16* kb = Kp + (size_t)b * SLK * DMODEL + h * DHEAD + lk * 8;
#pragma unroll 2
    for (int ct = 0; ct < 8; ++ct) {
        const int c0 = w * 128 + ct * 16;
        const bf16* kp = kb + (size_t)(c0 + lr) * DMODEL;
        bf16x8 b0 = *(const bf16x8*)kp;
        bf16x8 b1 = *(const bf16x8*)(kp + 32);
        f32x4 acc = {0.f, 0.f, 0.f, 0.f};
        acc = __builtin_amdgcn_mfma_f32_16x16x32_bf16(a0, b0, acc, 0, 0, 0);
        acc = __builtin_amdgcn_mfma_f32_16x16x32_bf16(a1, b1, acc, 0, 0, 0);
#pragma unroll
        for (int r = 0; r < 4; ++r)
            S[(lk * 4 + r) * SST + c0 + lr] = acc[r] * 0.125f;
    }
    __syncthreads();

    // ---- Phase B: wave w owns q-row w: bias + mask + stats ----
    {
        float* sp = &S[w * SST];
        const size_t brow = ((size_t)bh * SLQ + q0 + w) * SLK;
        const size_t mrow = ((size_t)b  * SLQ + q0 + w) * SLK;
        float mx = -3.0e38f;
#pragma unroll 2
        for (int j = 0; j < 8; ++j) {
            const int col = j * 256 + lane * 4;
            f32x4 v = *(const f32x4*)(sp + col);
            const float4 bb = *(const float4*)(bias + brow + col);
            const int4  mm = *(const int4*)(mask + mrow + col);
            float s0 = (mm.x == 0) ? -1e9f : v[0] + bb.x;
            float s1 = (mm.y == 0) ? -1e9f : v[1] + bb.y;
            float s2 = (mm.z == 0) ? -1e9f : v[2] + bb.z;
            float s3 = (mm.w == 0) ? -1e9f : v[3] + bb.w;
            f32x4 wv = {s0, s1, s2, s3};
            *(f32x4*)(sp + col) = wv;
            mx = fmaxf(mx, fmaxf(fmaxf(s0, s1), fmaxf(s2, s3)));
        }
#pragma unroll
        for (int d = 1; d < 64; d <<= 1) mx = fmaxf(mx, __shfl_xor(mx, d));
        float l = 0.f;
#pragma unroll 2
        for (int j = 0; j < 8; ++j) {
            const int col = j * 256 + lane * 4;
            const f32x4 v = *(const f32x4*)(sp + col);
            l += __expf(v[0] - mx) + __expf(v[1] - mx)
               + __expf(v[2] - mx) + __expf(v[3] - mx);
        }
#pragma unroll
        for (int d = 1; d < 64; d <<= 1) l += __shfl_xor(l, d);
        if (lane == 0) { m_s[w] = mx; inv_s[w] = 1.0f / l; }
    }
    __syncthreads();

    // ---- Phase D: per 512-col chunk: attn write + bf16 P -> PV MFMA ----
    f32x4 pv = {0.f, 0.f, 0.f, 0.f};
    const int g = w >> 2, dg = w & 3;
    const bf16* vb = Vt + (size_t)bh * DHEAD * SLK + (size_t)(dg * 16 + lr) * SLK + lk * 8;
    for (int c = 0; c < 4; ++c) {
        const int ck0 = c * 512;
        {   // row w, cols lane*8..lane*8+7 of this chunk
            const int scol = lane * 8;
            const float m = m_s[w], inv = inv_s[w];
            const f32x4 s0 = *(const f32x4*)&S[w * SST + ck0 + scol];
            const f32x4 s1 = *(const f32x4*)&S[w * SST + ck0 + scol + 4];
            const f32x4 p0 = {__expf(s0[0] - m) * inv, __expf(s0[1] - m) * inv,
                              __expf(s0[2] - m) * inv, __expf(s0[3] - m) * inv};
            const f32x4 p1 = {__expf(s1[0] - m) * inv, __expf(s1[1] - m) * inv,
                              __expf(s1[2] - m) * inv, __expf(s1[3] - m) * inv};
            float* ap = attn + ((size_t)bh * SLQ + q0 + w) * SLK + ck0 + scol;
            __builtin_nontemporal_store(p0, (f32x4*)ap);
            __builtin_nontemporal_store(p1, (f32x4*)(ap + 4));
            bf16 t8[8] = {__float2bfloat16(p0[0]), __float2bfloat16(p0[1]),
                          __float2bfloat16(p0[2]), __float2bfloat16(p0[3]),
                          __float2bfloat16(p1[0]), __float2bfloat16(p1[1]),
                          __float2bfloat16(p1[2]), __float2bfloat16(p1[3])};
            *(int4*)&Pc[w * PST + scol] = *(const int4*)t8;
        }
        __syncthreads();
        const bf16* vc = vb + ck0;
#pragma unroll
        for (int i = 0; i < 4; ++i) {
            const int koff = (g * 4 + i) * 32;
            bf16x8 pa = *(const bf16x8*)&Pc[lr * PST + koff + lk * 8];
            bf16x8 vv = *(const bf16x8*)(vc + koff);
            pv = __builtin_amdgcn_mfma_f32_16x16x32_bf16(pa, vv, pv, 0, 0, 0);
        }
        __syncthreads();
    }

    // ---- 4-way k-group reduction through dead S buffer, then ctx write ----
    float* rbuf = S;   // S is dead; 16KB staging
    *(f32x4*)&rbuf[(w * 64 + lane) * 4] = pv;
    __syncthreads();
    if (g == 0) {
        f32x4 t = {0.f, 0.f, 0.f, 0.f};
#pragma unroll
        for (int gg = 0; gg < 4; ++gg)
            t += *(const f32x4*)&rbuf[((gg * 4 + dg) * 64 + lane) * 4];
        const int d = dg * 16 + lr;
#pragma unroll
        for (int r = 0; r < 4; ++r) {
            const int q = lk * 4 + r;
            ctx[((size_t)(b * SLQ + q0 + q)) * DMODEL + h * DHEAD + d] =
                __float2bfloat16(t[r]);
        }
    }
}

// ---------------------------------------------------------------------------
// Memory plan (all global I/O f32; intermediates bf16):
//   d_out: out f32 [0..8MB) ‖ attn f32 [8MB..272MB)
//   Kp   = d_out[0..8MB) bf16      live: k_qkv -> k_attn (dead before projO)
//   qbf  = d_out[8..12MB)  bf16 \
//   kbf  = d_out[12..20MB) bf16  | live: k_cvt -> k_qkv; overwritten by
//   vbf  = d_out[20..28MB) bf16  | k_attn's attn store (dead by then)
//   Wqb/Wkb/Wvb = d_out[28..34MB)/
//   Qp   = ws[0..4MB)  bf16        live: k_qkv -> k_attn
//   ctx  = ws[0..4MB)  bf16        aliases Qp (k_attn per-block exact slices)
//   Wob  = ws[4..6MB)  bf16        live: k_cvt -> k_projO (survives k_attn)
//   Vt   = ws[8..16MB) bf16        live: k_qkv -> k_attn
// Peak ws = 16 MB.
// ---------------------------------------------------------------------------
extern "C" void kernel_launch(void* const* d_in, const int* in_sizes, int n_in,
                              void* d_out, int out_size, void* d_ws, size_t ws_size,
                              hipStream_t stream)
{
    const float* query = (const float*)d_in[0];
    const float* key   = (const float*)d_in[1];
    const float* value = (const float*)d_in[2];
    const int*   mask  = (const int*)d_in[3];
    const float* bias  = (const float*)d_in[4];
    const float* Wq = (const float*)d_in[5];
    const float* bq = (const float*)d_in[6];
    const float* Wk = (const float*)d_in[7];
    const float* bk = (const float*)d_in[8];
    const float* Wv = (const float*)d_in[9];
    const float* bv = (const float*)d_in[10];
    const float* Wo = (const float*)d_in[11];
    const float* bo = (const float*)d_in[12];

    float* out  = (float*)d_out;            // [B, Lq, D] f32
    float* attn = out + OUTQ;               // [B, H, Lq, Lk] f32

    bf16* Qp  = (bf16*)d_ws;                            // ws[0..4MB)
    bf16* ctx = Qp;                                     // alias (safe)
    bf16* Wob = Qp + (size_t)2 * 1024 * 1024;           // ws[4..6MB)
    bf16* Vt  = Qp + (size_t)4 * 1024 * 1024;           // ws[8..16MB)
    bf16* Kp  = (bf16*)d_out;                           // d_out[0..8MB)

    bf16* qbf = (bf16*)attn;                            // d_out[8..12MB)
    bf16* kbf = qbf + (size_t)2 * 1024 * 1024;          // [12..20MB)
    bf16* vbf = kbf + (size_t)4 * 1024 * 1024;          // [20..28MB)
    bf16* Wqb = vbf + (size_t)4 * 1024 * 1024;          // [28..30MB)
    bf16* Wkb = Wqb + (size_t)1024 * 1024;              // [30..32MB)
    bf16* Wvb = Wkb + (size_t)1024 * 1024;              // [32..34MB)

    k_cvt<<<dim3(256, 7), dim3(256), 0, stream>>>(query, key, value, Wq, Wk, Wv, Wo,
                                                  qbf, kbf, vbf, Wqb, Wkb, Wvb, Wob);
    k_qkv<<<dim3(32, 8, 3), dim3(256), 0, stream>>>(qbf, kbf, vbf, Wqb, Wkb, Wvb,
                                                    bq, bk, bv, Qp, Kp, Vt);
    k_attn<<<dim3(SLQ / 16, BATCH * NHEADS), dim3(1024), 0, stream>>>(Qp, Kp, bias, mask, Vt, attn, ctx);
    k_projO<<<dim3(16, 8), dim3(256), 0, stream>>>(ctx, Wob, bo, out);
}

// Round 6
// 698.966 us; speedup vs baseline: 1.2725x; 1.0133x over previous
//
#include <hip/hip_runtime.h>
#include <hip/hip_bf16.h>

typedef __hip_bfloat16 bf16;
typedef __bf16  bf16x8 __attribute__((ext_vector_type(8)));
typedef float   f32x4  __attribute__((ext_vector_type(4)));

static constexpr int DMODEL = 1024;
static constexpr int NHEADS = 16;
static constexpr int DHEAD  = 64;
static constexpr int BATCH  = 2;
static constexpr int SLQ    = 1024;
static constexpr int SLK    = 2048;
static constexpr size_t OUTQ = (size_t)BATCH * SLQ * DMODEL;   // out elems (f32)

// width-16 async global->LDS (wave-uniform LDS base; HW adds lane*16)
#define GLOAD16(g, l) __builtin_amdgcn_global_load_lds(                        \
    (const __attribute__((address_space(1))) unsigned int*)(g),                \
    (__attribute__((address_space(3))) unsigned int*)(l), 16, 0, 0)

// ---------------------------------------------------------------------------
// k_cvt: one-shot f32 -> bf16 conversion of q/k/v inputs + 4 weight matrices.
// grid = (256, 7); seg = blockIdx.y picks the array.
// ---------------------------------------------------------------------------
__global__ __launch_bounds__(256)
void k_cvt(const float* __restrict__ q,  const float* __restrict__ k,
           const float* __restrict__ v,  const float* __restrict__ wq,
           const float* __restrict__ wk, const float* __restrict__ wv,
           const float* __restrict__ wo,
           bf16* __restrict__ qb,  bf16* __restrict__ kb,  bf16* __restrict__ vb,
           bf16* __restrict__ wqb, bf16* __restrict__ wkb, bf16* __restrict__ wvb,
           bf16* __restrict__ wob)
{
    const int seg = blockIdx.y;
    const float* s; bf16* d; int n;
    switch (seg) {
        case 0:  s = q;  d = qb;  n = 2 * 1024 * 1024; break;
        case 1:  s = k;  d = kb;  n = 4 * 1024 * 1024; break;
        case 2:  s = v;  d = vb;  n = 4 * 1024 * 1024; break;
        case 3:  s = wq; d = wqb; n = 1024 * 1024; break;
        case 4:  s = wk; d = wkb; n = 1024 * 1024; break;
        case 5:  s = wv; d = wvb; n = 1024 * 1024; break;
        default: s = wo; d = wob; n = 1024 * 1024; break;
    }
    const int stride = gridDim.x * blockDim.x;
    for (int i = blockIdx.x * blockDim.x + threadIdx.x; i * 8 < n; i += stride) {
        const float4 a = *(const float4*)(s + (size_t)i * 8);
        const float4 b = *(const float4*)(s + (size_t)i * 8 + 4);
        bf16 h[8] = {__float2bfloat16(a.x), __float2bfloat16(a.y),
                     __float2bfloat16(a.z), __float2bfloat16(a.w),
                     __float2bfloat16(b.x), __float2bfloat16(b.y),
                     __float2bfloat16(b.z), __float2bfloat16(b.w)};
        *(int4*)(d + (size_t)i * 8) = *(const int4*)h;
    }
}

// ---------------------------------------------------------------------------
// 128x128-tile bf16 GEMM core, m97 structure: global_load_lds width-16 into
// LINEAR LDS [128][32] (staging = pure DMA, no VGPR round trip).
// 256 thr = 4 waves in 2x2, each wave 64x64 via acc[4][4] of 16x16x32 MFMA.
// Staging: wave w stages rows [w*32, w*32+32) as two 16-row/1KB segments;
//          lane l <-> row seg*16 + l/4, col (l&3)*8  (dest = base + l*16).
// ---------------------------------------------------------------------------
__device__ __forceinline__ void gemm128(const bf16* __restrict__ A,
                                        const bf16* __restrict__ W,
                                        int m0, int n0, f32x4 acc[4][4])
{
    __shared__ __align__(16) unsigned short As[128 * 32];
    __shared__ __align__(16) unsigned short Bs[128 * 32];
    const int tid  = threadIdx.x;
    const int lane = tid & 63, w = tid >> 6;
    const int wr = (w >> 1) * 64, wc = (w & 1) * 64;
    const int lr = lane & 15, lk = lane >> 4;

    const int seg0 = w * 2, seg1 = w * 2 + 1;
    const int r0 = seg0 * 16 + (lane >> 2);
    const int r1 = seg1 * 16 + (lane >> 2);
    const int ce = (lane & 3) * 8;
    const bf16* a0p = A + (size_t)(m0 + r0) * DMODEL + ce;
    const bf16* a1p = A + (size_t)(m0 + r1) * DMODEL + ce;
    const bf16* w0p = W + (size_t)(n0 + r0) * DMODEL + ce;
    const bf16* w1p = W + (size_t)(n0 + r1) * DMODEL + ce;
    unsigned short* as0 = &As[seg0 * 512];
    unsigned short* as1 = &As[seg1 * 512];
    unsigned short* bs0 = &Bs[seg0 * 512];
    unsigned short* bs1 = &Bs[seg1 * 512];

    for (int kt = 0; kt < DMODEL; kt += 32) {
        GLOAD16(a0p + kt, as0);
        GLOAD16(a1p + kt, as1);
        GLOAD16(w0p + kt, bs0);
        GLOAD16(w1p + kt, bs1);
        __syncthreads();
        bf16x8 av[4], wv[4];
#pragma unroll
        for (int i = 0; i < 4; ++i)
            av[i] = *(const bf16x8*)&As[(wr + i * 16 + lr) * 32 + lk * 8];
#pragma unroll
        for (int j = 0; j < 4; ++j)
            wv[j] = *(const bf16x8*)&Bs[(wc + j * 16 + lr) * 32 + lk * 8];
#pragma unroll
        for (int i = 0; i < 4; ++i)
#pragma unroll
            for (int j = 0; j < 4; ++j)
                acc[i][j] = __builtin_amdgcn_mfma_f32_16x16x32_bf16(av[i], wv[j], acc[i][j], 0, 0, 0);
        __syncthreads();
    }
}

// ---------------------------------------------------------------------------
// Fused Q/K/V projections: blockIdx.z = which (0:Q, 1:K, 2:V-transposed).
// grid = (32, 8, 3); Q blocks with m0 >= 2048 exit early.
// ---------------------------------------------------------------------------
__global__ __launch_bounds__(256)
void k_qkv(const bf16* __restrict__ qb, const bf16* __restrict__ kb,
           const bf16* __restrict__ vb2,
           const bf16* __restrict__ wqb, const bf16* __restrict__ wkb,
           const bf16* __restrict__ wvb,
           const float* __restrict__ bq, const float* __restrict__ bk,
           const float* __restrict__ bvv,
           bf16* __restrict__ Qp, bf16* __restrict__ Kp, bf16* __restrict__ Vt)
{
    const int which = blockIdx.z;
    const int m0 = blockIdx.x * 128, n0 = blockIdx.y * 128;
    if (which == 0 && m0 >= BATCH * SLQ) return;
    const bf16* A = which == 0 ? qb : which == 1 ? kb : vb2;
    const bf16* W = which == 0 ? wqb : which == 1 ? wkb : wvb;
    const float* bias = which == 0 ? bq : which == 1 ? bk : bvv;

    f32x4 acc[4][4] = {};
    gemm128(A, W, m0, n0, acc);

    const int tid = threadIdx.x, lane = tid & 63, w = tid >> 6;
    const int wr = (w >> 1) * 64, wc = (w & 1) * 64;
    const int lr = lane & 15, lk = lane >> 4;

    if (which < 2) {
        bf16* C = which == 0 ? Qp : Kp;
#pragma unroll
        for (int i = 0; i < 4; ++i)
#pragma unroll
            for (int j = 0; j < 4; ++j) {
                const int col = n0 + wc + j * 16 + lr;
                const float bvx = bias[col];
#pragma unroll
                for (int r = 0; r < 4; ++r) {
                    const int row = m0 + wr + i * 16 + lk * 4 + r;
                    C[(size_t)row * DMODEL + col] = __float2bfloat16(acc[i][j][r] + bvx);
                }
            }
    } else {
#pragma unroll
        for (int i = 0; i < 4; ++i)
#pragma unroll
            for (int j = 0; j < 4; ++j) {
                const int col = n0 + wc + j * 16 + lr;
                const float bvx = bias[col];
                const int h = col >> 6, d = col & 63;
                const int mb = m0 + wr + i * 16 + lk * 4;   // multiple of 4
                const int b = mb >> 11, kk = mb & 2047;
                bf16* dst = Vt + ((size_t)(b * NHEADS + h) * DHEAD + d) * SLK + kk;
#pragma unroll
                for (int r = 0; r < 4; ++r)
                    dst[r] = __float2bfloat16(acc[i][j][r] + bvx);
            }
    }
}

// ---------------------------------------------------------------------------
// Output projection: out[2048x1024] f32 = ctx(bf16) * Wo^T + bo.  grid (16,8).
// ---------------------------------------------------------------------------
__global__ __launch_bounds__(256)
void k_projO(const bf16* __restrict__ ctx, const bf16* __restrict__ wob,
             const float* __restrict__ bo, float* __restrict__ out)
{
    const int m0 = blockIdx.x * 128, n0 = blockIdx.y * 128;
    f32x4 acc[4][4] = {};
    gemm128(ctx, wob, m0, n0, acc);
    const int tid = threadIdx.x, lane = tid & 63, w = tid >> 6;
    const int wr = (w >> 1) * 64, wc = (w & 1) * 64;
    const int lr = lane & 15, lk = lane >> 4;
#pragma unroll
    for (int i = 0; i < 4; ++i)
#pragma unroll
        for (int j = 0; j < 4; ++j) {
            const int col = n0 + wc + j * 16 + lr;
            const float bvx = bo[col];
#pragma unroll
            for (int r = 0; r < 4; ++r) {
                const int row = m0 + wr + i * 16 + lk * 4 + r;
                out[(size_t)row * DMODEL + col] = acc[i][j][r] + bvx;
            }
        }
}

// ---------------------------------------------------------------------------
// Fused attention: scores (+bias +mask) -> softmax -> attn write -> P·V.
// One block = one (b,h) head x 16 q-rows x full Lk=2048.  1024 thr = 16 waves.
//   Prefetch: bias+mask row w into REGISTERS at kernel entry (64 VGPR) so the
//             ~260MB of HBM reads fly under phase A's QK^T (round-5 fix).
//   Phase A: wave w computes cols [w*128, w*128+128) of S = QK^T * 0.125
//   Phase B: wave w owns q-row w: combine reg bias/mask + LDS S, stats
//   Phase D: per 512-col chunk: wave w = (kgroup g=w>>2, dgroup dg=w&3)
//            p=exp(s-m)*inv -> attn (nontemporal) + bf16 Pc; 4 MFMA per wave;
//            final 4-way k-group reduction staged through dead S buffer.
// LDS: 131328 (S) + 16640 (Pc) + 128 = 148096 B  (1 block/CU, 16 waves)
// ---------------------------------------------------------------------------
__global__ __launch_bounds__(1024, 4)
void k_attn(const bf16* __restrict__ Qp, const bf16* __restrict__ Kp,
            const float* __restrict__ bias, const int* __restrict__ mask,
            const bf16* __restrict__ Vt, float* __restrict__ attn,
            bf16* __restrict__ ctx)
{
    constexpr int SST = 2052;   // f32 stride
    constexpr int PST = 520;    // bf16 stride

    __shared__ __align__(16) float S[16 * SST];
    __shared__ __align__(16) bf16  Pc[16 * PST];
    __shared__ float m_s[16], inv_s[16];

    const int qt = blockIdx.x, bh = blockIdx.y;
    const int b = bh >> 4, h = bh & 15;
    const int q0 = qt * 16;
    const int tid  = threadIdx.x;
    const int lane = tid & 63, w = tid >> 6;
    const int lr = lane & 15, lk = lane >> 4;

    // ---- prefetch bias + mask for q-row w (in flight during phase A) ----
    f32x4 bb[8]; int4 mm[8];
    {
        const size_t brow = ((size_t)bh * SLQ + q0 + w) * SLK;
        const size_t mrow = ((size_t)b  * SLQ + q0 + w) * SLK;
#pragma unroll
        for (int j = 0; j < 8; ++j) {
            bb[j] = *(const f32x4*)(bias + brow + j * 256 + lane * 4);
            mm[j] = *(const int4*)(mask + mrow + j * 256 + lane * 4);
        }
    }

    // ---- Q fragments (rows q0..q0+15 of head h), K=64 -> two frags ----
    const bf16* qb = Qp + ((size_t)(b * SLQ + q0 + lr)) * DMODEL + h * DHEAD + lk * 8;
    const bf16x8 a0 = *(const bf16x8*)qb;
    const bf16x8 a1 = *(const bf16x8*)(qb + 32);

    // ---- Phase A: S = (Q.K^T) * 0.125  (wave w: 128-col strip) ----
    const bf16* kb = Kp + (size_t)b * SLK * DMODEL + h * DHEAD + lk * 8;
#pragma unroll 2
    for (int ct = 0; ct < 8; ++ct) {
        const int c0 = w * 128 + ct * 16;
        const bf16* kp = kb + (size_t)(c0 + lr) * DMODEL;
        bf16x8 b0 = *(const bf16x8*)kp;
        bf16x8 b1 = *(const bf16x8*)(kp + 32);
        f32x4 acc = {0.f, 0.f, 0.f, 0.f};
        acc = __builtin_amdgcn_mfma_f32_16x16x32_bf16(a0, b0, acc, 0, 0, 0);
        acc = __builtin_amdgcn_mfma_f32_16x16x32_bf16(a1, b1, acc, 0, 0, 0);
#pragma unroll
        for (int r = 0; r < 4; ++r)
            S[(lk * 4 + r) * SST + c0 + lr] = acc[r] * 0.125f;
    }
    __syncthreads();

    // ---- Phase B: wave w owns q-row w: combine (regs) + stats ----
    {
        float* sp = &S[w * SST];
        float mx = -3.0e38f;
#pragma unroll
        for (int j = 0; j < 8; ++j) {
            const int col = j * 256 + lane * 4;
            f32x4 v = *(const f32x4*)(sp + col);
            float s0 = (mm[j].x == 0) ? -1e9f : v[0] + bb[j][0];
            float s1 = (mm[j].y == 0) ? -1e9f : v[1] + bb[j][1];
            float s2 = (mm[j].z == 0) ? -1e9f : v[2] + bb[j][2];
            float s3 = (mm[j].w == 0) ? -1e9f : v[3] + bb[j][3];
            f32x4 wv = {s0, s1, s2, s3};
            *(f32x4*)(sp + col) = wv;
            mx = fmaxf(mx, fmaxf(fmaxf(s0, s1), fmaxf(s2, s3)));
        }
#pragma unroll
        for (int d = 1; d < 64; d <<= 1) mx = fmaxf(mx, __shfl_xor(mx, d));
        float l = 0.f;
#pragma unroll 2
        for (int j = 0; j < 8; ++j) {
            const int col = j * 256 + lane * 4;
            const f32x4 v = *(const f32x4*)(sp + col);
            l += __expf(v[0] - mx) + __expf(v[1] - mx)
               + __expf(v[2] - mx) + __expf(v[3] - mx);
        }
#pragma unroll
        for (int d = 1; d < 64; d <<= 1) l += __shfl_xor(l, d);
        if (lane == 0) { m_s[w] = mx; inv_s[w] = 1.0f / l; }
    }
    __syncthreads();

    // ---- Phase D: per 512-col chunk: attn write + bf16 P -> PV MFMA ----
    f32x4 pv = {0.f, 0.f, 0.f, 0.f};
    const int g = w >> 2, dg = w & 3;
    const bf16* vb = Vt + (size_t)bh * DHEAD * SLK + (size_t)(dg * 16 + lr) * SLK + lk * 8;
    for (int c = 0; c < 4; ++c) {
        const int ck0 = c * 512;
        {   // row w, cols lane*8..lane*8+7 of this chunk
            const int scol = lane * 8;
            const float m = m_s[w], inv = inv_s[w];
            const f32x4 s0 = *(const f32x4*)&S[w * SST + ck0 + scol];
            const f32x4 s1 = *(const f32x4*)&S[w * SST + ck0 + scol + 4];
            const f32x4 p0 = {__expf(s0[0] - m) * inv, __expf(s0[1] - m) * inv,
                              __expf(s0[2] - m) * inv, __expf(s0[3] - m) * inv};
            const f32x4 p1 = {__expf(s1[0] - m) * inv, __expf(s1[1] - m) * inv,
                              __expf(s1[2] - m) * inv, __expf(s1[3] - m) * inv};
            float* ap = attn + ((size_t)bh * SLQ + q0 + w) * SLK + ck0 + scol;
            __builtin_nontemporal_store(p0, (f32x4*)ap);
            __builtin_nontemporal_store(p1, (f32x4*)(ap + 4));
            bf16 t8[8] = {__float2bfloat16(p0[0]), __float2bfloat16(p0[1]),
                          __float2bfloat16(p0[2]), __float2bfloat16(p0[3]),
                          __float2bfloat16(p1[0]), __float2bfloat16(p1[1]),
                          __float2bfloat16(p1[2]), __float2bfloat16(p1[3])};
            *(int4*)&Pc[w * PST + scol] = *(const int4*)t8;
        }
        __syncthreads();
        const bf16* vc = vb + ck0;
#pragma unroll
        for (int i = 0; i < 4; ++i) {
            const int koff = (g * 4 + i) * 32;
            bf16x8 pa = *(const bf16x8*)&Pc[lr * PST + koff + lk * 8];
            bf16x8 vv = *(const bf16x8*)(vc + koff);
            pv = __builtin_amdgcn_mfma_f32_16x16x32_bf16(pa, vv, pv, 0, 0, 0);
        }
        __syncthreads();
    }

    // ---- 4-way k-group reduction through dead S buffer, then ctx write ----
    float* rbuf = S;   // S is dead; 16KB staging
    *(f32x4*)&rbuf[(w * 64 + lane) * 4] = pv;
    __syncthreads();
    if (g == 0) {
        f32x4 t = {0.f, 0.f, 0.f, 0.f};
#pragma unroll
        for (int gg = 0; gg < 4; ++gg)
            t += *(const f32x4*)&rbuf[((gg * 4 + dg) * 64 + lane) * 4];
        const int d = dg * 16 + lr;
#pragma unroll
        for (int r = 0; r < 4; ++r) {
            const int q = lk * 4 + r;
            ctx[((size_t)(b * SLQ + q0 + q)) * DMODEL + h * DHEAD + d] =
                __float2bfloat16(t[r]);
        }
    }
}

// ---------------------------------------------------------------------------
// Memory plan (all global I/O f32; intermediates bf16):
//   d_out: out f32 [0..8MB) ‖ attn f32 [8MB..272MB)
//   Kp   = d_out[0..8MB) bf16      live: k_qkv -> k_attn (dead before projO)
//   qbf  = d_out[8..12MB)  bf16 \
//   kbf  = d_out[12..20MB) bf16  | live: k_cvt -> k_qkv; overwritten by
//   vbf  = d_out[20..28MB) bf16  | k_attn's attn store (dead by then)
//   Wqb/Wkb/Wvb = d_out[28..34MB)/
//   Qp   = ws[0..4MB)  bf16        live: k_qkv -> k_attn
//   ctx  = ws[0..4MB)  bf16        aliases Qp (k_attn per-block exact slices)
//   Wob  = ws[4..6MB)  bf16        live: k_cvt -> k_projO (survives k_attn)
//   Vt   = ws[8..16MB) bf16        live: k_qkv -> k_attn
// Peak ws = 16 MB.
// ---------------------------------------------------------------------------
extern "C" void kernel_launch(void* const* d_in, const int* in_sizes, int n_in,
                              void* d_out, int out_size, void* d_ws, size_t ws_size,
                              hipStream_t stream)
{
    const float* query = (const float*)d_in[0];
    const float* key   = (const float*)d_in[1];
    const float* value = (const float*)d_in[2];
    const int*   mask  = (const int*)d_in[3];
    const float* bias  = (const float*)d_in[4];
    const float* Wq = (const float*)d_in[5];
    const float* bq = (const float*)d_in[6];
    const float* Wk = (const float*)d_in[7];
    const float* bk = (const float*)d_in[8];
    const float* Wv = (const float*)d_in[9];
    const float* bv = (const float*)d_in[10];
    const float* Wo = (const float*)d_in[11];
    const float* bo = (const float*)d_in[12];

    float* out  = (float*)d_out;            // [B, Lq, D] f32
    float* attn = out + OUTQ;               // [B, H, Lq, Lk] f32

    bf16* Qp  = (bf16*)d_ws;                            // ws[0..4MB)
    bf16* ctx = Qp;                                     // alias (safe)
    bf16* Wob = Qp + (size_t)2 * 1024 * 1024;           // ws[4..6MB)
    bf16* Vt  = Qp + (size_t)4 * 1024 * 1024;           // ws[8..16MB)
    bf16* Kp  = (bf16*)d_out;                           // d_out[0..8MB)

    bf16* qbf = (bf16*)attn;                            // d_out[8..12MB)
    bf16* kbf = qbf + (size_t)2 * 1024 * 1024;          // [12..20MB)
    bf16* vbf = kbf + (size_t)4 * 1024 * 1024;          // [20..28MB)
    bf16* Wqb = vbf + (size_t)4 * 1024 * 1024;          // [28..30MB)
    bf16* Wkb = Wqb + (size_t)1024 * 1024;              // [30..32MB)
    bf16* Wvb = Wkb + (size_t)1024 * 1024;              // [32..34MB)

    k_cvt<<<dim3(256, 7), dim3(256), 0, stream>>>(query, key, value, Wq, Wk, Wv, Wo,
                                                  qbf, kbf, vbf, Wqb, Wkb, Wvb, Wob);
    k_qkv<<<dim3(32, 8, 3), dim3(256), 0, stream>>>(qbf, kbf, vbf, Wqb, Wkb, Wvb,
                                                    bq, bk, bv, Qp, Kp, Vt);
    k_attn<<<dim3(SLQ / 16, BATCH * NHEADS), dim3(1024), 0, stream>>>(Qp, Kp, bias, mask, Vt, attn, ctx);
    k_projO<<<dim3(16, 8), dim3(256), 0, stream>>>(ctx, Wob, bo, out);
}